// Round 7
// baseline (134.208 us; speedup 1.0000x reference)
//
#include <hip/hip_runtime.h>
#include <math.h>

// FocalLoss (rotated-box RetinaNet style), MI355X.
// B=8 images, A=120000 anchors, C=9 classes, M=64 annotations.
// out = [mean cls_loss, mean reg_loss] (2 floats).
//
// R7 structure: 1-wave blocks (TPB=64) x R=4 anchors/thread -> 3752 blocks
// (~14.7 waves/CU, was 3.7 at R6's 944x4-wave grid -> occupancy was 25%).
// cls probs preloaded into regs before the argmax loop (latency hidden).
// pos/neg decided on the rational (bestA vs 0.5*bestB) -> no f32 division.
// Invalid anns staged as all-zero boxes: inter==0, s==0 -> av==0 can never
// win the strict-greater argmax; all-invalid image is discarded via has_ann.

constexpr int Bn = 8, An = 120000, Cn = 9, Mn = 64;
constexpr int R = 4;                       // anchors per thread
constexpr int TPB = 64;                    // one wave per block
constexpr int APB = TPB * R;               // anchors per block = 256
constexpr int GX = (An + APB - 1) / APB;   // 469 blocks per image

typedef float f4 __attribute__((ext_vector_type(4), aligned(4)));
typedef float f2 __attribute__((ext_vector_type(2), aligned(4)));

// ws: per-block partials, block j=(b*GX+bx): [j*4 + {0:cls,1:reg,2:pos}]
__global__ __launch_bounds__(TPB) void focal_main(
    const float* __restrict__ cls,
    const float* __restrict__ reg,
    const float* __restrict__ anchors,
    const float* __restrict__ ann,
    float* __restrict__ ws)
{
    // sT[k][0] = {x1,y1,x2,y2}; sT[k][1] = {sin,cos,area,clsval}
    __shared__ float4 sT[Mn][2];

    const int tid = threadIdx.x;           // 0..63
    const int b = blockIdx.y;
    const int base = blockIdx.x * APB + tid;

    {   // stage annotation tile (Mn == TPB: every lane stages one ann)
        const float* a6 = ann + ((size_t)b * Mn + tid) * 6;
        f4 v0 = *(const f4*)a6;            // x1,y1,x2,y2
        f2 v1 = *(const f2*)(a6 + 4);      // clsval, flag
        float x1 = v0.x, y1 = v0.y, x2 = v0.z, y2 = v0.w, cv = v1.x;
        float sb, cb;
        sincosf(cv, &sb, &cb);
        if (v1.y == -1.0f) { x1 = y1 = x2 = y2 = 0.f; sb = cb = 0.f; cv = 0.f; }
        sT[tid][0] = make_float4(x1, y1, x2, y2);
        sT[tid][1] = make_float4(sb, cb, (x2 - x1) * (y2 - y1), cv);
    }
    __syncthreads();

    // per-anchor persistent state
    float ax1[R], ay1[R], ax2[R], ay2[R], areaA[R], sa[R], ca[R], aangv[R];
    float bestA[R], bestB[R];
    int bestK[R];
    bool act[R];
    f4 c0[R], c1[R];
    float c8[R];

    #pragma unroll
    for (int r = 0; r < R; ++r) {
        const int i = base + r * TPB;
        act[r] = (i < An);
        const int ii = act[r] ? i : (An - 1);   // clamp: no OOB reads
        bestA[r] = 0.f; bestB[r] = 1.f; bestK[r] = 0;
        const float* a5 = anchors + (size_t)ii * 5;
        f4 av5 = *(const f4*)a5;
        ax1[r] = av5.x; ay1[r] = av5.y; ax2[r] = av5.z; ay2[r] = av5.w;
        aangv[r] = a5[4];
        areaA[r] = (ax2[r] - ax1[r]) * (ay2[r] - ay1[r]);
        sincosf(aangv[r], &sa[r], &ca[r]);
        // preload cls probs now; latency hides under the argmax loop
        const float* pc = cls + ((size_t)b * An + ii) * (size_t)Cn;
        c0[r] = *(const f4*)pc;
        c1[r] = *(const f4*)(pc + 4);
        c8[r] = pc[8];
    }

    // argmax of ariou = (inter/ua)*|sin(aang-bang)| as rational (bestA/bestB).
    // cos(|d|-pi/2) == |sin d| for |d|<=pi (holds: aang in [0,pi), bang in {1,2,3}).
    // Strict-greater update -> first-occurrence, matching jnp.argmax.
    #pragma unroll 4
    for (int k = 0; k < Mn; ++k) {
        const float4 bx = sT[k][0];
        const float4 au = sT[k][1];   // {sinb, cosb, areaB, clsval}
        #pragma unroll
        for (int r = 0; r < R; ++r) {
            float iw = fminf(ax2[r], bx.z) - fmaxf(ax1[r], bx.x);
            float ih = fminf(ay2[r], bx.w) - fmaxf(ay1[r], bx.y);
            iw = fmaxf(iw, 0.f); ih = fmaxf(ih, 0.f);
            float inter = iw * ih;
            float ua = fmaxf(areaA[r] + au.z - inter, 1e-8f);
            float s = fabsf(sa[r] * au.y - ca[r] * au.x);   // |sin(aang-bang)|
            float av = inter * s;
            bool upd = (av * bestB[r] > bestA[r] * ua);
            bestA[r] = upd ? av : bestA[r];
            bestB[r] = upd ? ua : bestB[r];
            bestK[r] = upd ? k : bestK[r];
        }
    }

    float csum = 0.f, rsum = 0.f, pcnt = 0.f;

    #pragma unroll
    for (int r = 0; r < R; ++r) {
        if (!act[r]) continue;
        const int i = base + r * TPB;
        // iou >= 0.5  <=>  bestA >= 0.5*bestB   (bestB > 0; no division)
        const bool pos = bestA[r] >= 0.5f * bestB[r];
        const bool neg = bestA[r] <  0.4f * bestB[r];

        if (pos || neg) {
            const float4 au = sT[bestK[r]][1];
            const int ci = (int)au.w;
            float pv[9] = { c0[r].x, c0[r].y, c0[r].z, c0[r].w,
                            c1[r].x, c1[r].y, c1[r].z, c1[r].w, c8[r] };
            #pragma unroll
            for (int c = 0; c < Cn; ++c) {
                float p = fminf(fmaxf(pv[c], 1e-4f), 0.9999f);
                bool hit = pos && (c == ci);
                float t = hit ? (1.f - p) : p;   // focal base
                float m = hit ? p : (1.f - p);   // log argument
                float w = hit ? 0.25f : 0.75f;
                csum += w * t * t * (-__logf(m));
            }
        }

        if (pos) {
            pcnt += 1.f;
            const float4 gb = sT[bestK[r]][0];
            const float4 au = sT[bestK[r]][1];
            float aw = ax2[r] - ax1[r], ah = ay2[r] - ay1[r];
            float acx = ax1[r] + 0.5f * aw, acy = ay1[r] + 0.5f * ah;
            float gwr = gb.z - gb.x, ghr = gb.w - gb.y;
            float gcx = gb.x + 0.5f * gwr, gcy = gb.y + 0.5f * ghr;
            float gw = fmaxf(gwr, 1.f), gh = fmaxf(ghr, 1.f);
            float tt[5];
            tt[0] = ((gcx - acx) / aw) * 10.f;
            tt[1] = ((gcy - acy) / ah) * 10.f;
            tt[2] = logf(gw / aw) * 5.f;
            tt[3] = logf(gh / ah) * 5.f;
            tt[4] = tanf(au.w - aangv[r]);
            const float* rg = reg + ((size_t)b * An + i) * 5;
            #pragma unroll
            for (int j = 0; j < 5; ++j) {
                float d = fabsf(tt[j] - rg[j]);
                rsum += (d <= (1.f / 9.f)) ? (4.5f * d * d) : (d - (0.5f / 9.f));
            }
        }
    }

    // single-wave block: shuffle reduce, lane 0 writes the block partial
    #pragma unroll
    for (int off = 32; off > 0; off >>= 1) {
        csum += __shfl_down(csum, off, 64);
        rsum += __shfl_down(rsum, off, 64);
        pcnt += __shfl_down(pcnt, off, 64);
    }
    if (tid == 0) {
        const int j = b * GX + blockIdx.x;
        ws[j * 4 + 0] = csum;   // unconditional writes: no memset needed
        ws[j * 4 + 1] = rsum;
        ws[j * 4 + 2] = pcnt;
    }
}

// 8 waves, wave w reduces image w's GX partials; then thread 0 means over B.
__global__ __launch_bounds__(512) void focal_final(
    const float* __restrict__ ann,
    const float* __restrict__ ws,
    float* __restrict__ out)
{
    __shared__ float simg[Bn][2];
    const int tid = threadIdx.x;
    const int w = tid >> 6;      // image
    const int lane = tid & 63;

    float c = 0.f, r = 0.f, p = 0.f;
    for (int j = lane; j < GX; j += 64) {
        const int idx = (w * GX + j) * 4;
        c += ws[idx + 0]; r += ws[idx + 1]; p += ws[idx + 2];
    }
    // has_ann: lane k checks ann[w][k] (Mn==64 lanes exactly)
    float fl = ann[((size_t)w * Mn + lane) * 6 + 5];
    bool has = __any(fl != -1.0f);

    #pragma unroll
    for (int off = 32; off > 0; off >>= 1) {
        c += __shfl_down(c, off, 64);
        r += __shfl_down(r, off, 64);
        p += __shfl_down(p, off, 64);
    }
    if (lane == 0) {
        float cl = 0.f, rl = 0.f;
        if (has) {
            cl = c / fmaxf(p, 1.f);
            rl = (p > 0.f) ? r / fmaxf(p * 5.f, 1.f) : 0.f;
        }
        simg[w][0] = cl; simg[w][1] = rl;
    }
    __syncthreads();
    if (tid == 0) {
        float cl = 0.f, rl = 0.f;
        #pragma unroll
        for (int b = 0; b < Bn; ++b) { cl += simg[b][0]; rl += simg[b][1]; }
        out[0] = cl / (float)Bn;
        out[1] = rl / (float)Bn;
    }
}

extern "C" void kernel_launch(void* const* d_in, const int* in_sizes, int n_in,
                              void* d_out, int out_size, void* d_ws, size_t ws_size,
                              hipStream_t stream) {
    const float* cls     = (const float*)d_in[0];  // (B, A, C)
    const float* reg     = (const float*)d_in[1];  // (B, A, 5)
    const float* anchors = (const float*)d_in[2];  // (1, A, 5)
    const float* ann     = (const float*)d_in[3];  // (B, M, 6)
    float* out = (float*)d_out;
    float* ws  = (float*)d_ws;

    dim3 grid(GX, Bn);
    focal_main<<<grid, TPB, 0, stream>>>(cls, reg, anchors, ann, ws);
    focal_final<<<1, 512, 0, stream>>>(ann, ws, out);
}

// Round 10
// 127.494 us; speedup vs baseline: 1.0527x; 1.0527x over previous
//
#include <hip/hip_runtime.h>
#include <math.h>

// FocalLoss (rotated-box RetinaNet style), MI355X.
// B=8 images, A=120000 anchors, C=9 classes, M=64 annotations.
// out = [mean cls_loss, mean reg_loss] (2 floats).
//
// R8 structure: R=2 anchors/thread (total waves = B*A/(64*R) = 7520
// ~= 7.3/SIMD -- R7 showed total wave COUNT, not block shape, is the
// occupancy lever; R=4 capped the whole grid at 3.7 waves/SIMD).
// TPB=256 (4-wave workgroups, 1880 blocks). cls probs preloaded into
// regs before the argmax loop. pos/neg via rational compare (no fdiv).
// Invalid anns staged as all-zero boxes: av==0 never wins strict-greater
// argmax; all-invalid image discarded via has_ann in focal_final.

constexpr int Bn = 8, An = 120000, Cn = 9, Mn = 64;
constexpr int R = 2;                       // anchors per thread
constexpr int TPB = 256;
constexpr int APB = TPB * R;               // anchors per block = 512
constexpr int GX = (An + APB - 1) / APB;   // 235 blocks per image

typedef float f4 __attribute__((ext_vector_type(4), aligned(4)));
typedef float f2 __attribute__((ext_vector_type(2), aligned(4)));

// ws: per-block partials, block j=(b*GX+bx): [j*4 + {0:cls,1:reg,2:pos}]
__global__ __launch_bounds__(TPB) void focal_main(
    const float* __restrict__ cls,
    const float* __restrict__ reg,
    const float* __restrict__ anchors,
    const float* __restrict__ ann,
    float* __restrict__ ws)
{
    // sT[k][0] = {x1,y1,x2,y2}; sT[k][1] = {sin,cos,area,clsval}
    __shared__ float4 sT[Mn][2];
    __shared__ float sred[4][3];

    const int tid = threadIdx.x;
    const int b = blockIdx.y;
    const int base = blockIdx.x * APB + tid;

    if (tid < Mn) {   // stage annotation tile
        const float* a6 = ann + ((size_t)b * Mn + tid) * 6;
        f4 v0 = *(const f4*)a6;            // x1,y1,x2,y2
        f2 v1 = *(const f2*)(a6 + 4);      // clsval, flag
        float x1 = v0.x, y1 = v0.y, x2 = v0.z, y2 = v0.w, cv = v1.x;
        float sb, cb;
        sincosf(cv, &sb, &cb);
        if (v1.y == -1.0f) { x1 = y1 = x2 = y2 = 0.f; sb = cb = 0.f; cv = 0.f; }
        sT[tid][0] = make_float4(x1, y1, x2, y2);
        sT[tid][1] = make_float4(sb, cb, (x2 - x1) * (y2 - y1), cv);
    }
    __syncthreads();

    // per-anchor persistent state
    float ax1[R], ay1[R], ax2[R], ay2[R], areaA[R], sa[R], ca[R], aangv[R];
    float bestA[R], bestB[R];
    int bestK[R];
    bool act[R];
    f4 c0[R], c1[R];
    float c8[R];

    #pragma unroll
    for (int r = 0; r < R; ++r) {
        const int i = base + r * TPB;
        act[r] = (i < An);
        const int ii = act[r] ? i : (An - 1);   // clamp: no OOB reads
        bestA[r] = 0.f; bestB[r] = 1.f; bestK[r] = 0;
        const float* a5 = anchors + (size_t)ii * 5;
        f4 av5 = *(const f4*)a5;
        ax1[r] = av5.x; ay1[r] = av5.y; ax2[r] = av5.z; ay2[r] = av5.w;
        aangv[r] = a5[4];
        areaA[r] = (ax2[r] - ax1[r]) * (ay2[r] - ay1[r]);
        sincosf(aangv[r], &sa[r], &ca[r]);
        // preload cls probs now; latency hides under the argmax loop
        const float* pc = cls + ((size_t)b * An + ii) * (size_t)Cn;
        c0[r] = *(const f4*)pc;
        c1[r] = *(const f4*)(pc + 4);
        c8[r] = pc[8];
    }

    // argmax of ariou = (inter/ua)*|sin(aang-bang)| as rational (bestA/bestB).
    // cos(|d|-pi/2) == |sin d| for |d|<=pi (holds: aang in [0,pi), bang in {1,2,3}).
    // Strict-greater update -> first-occurrence, matching jnp.argmax.
    #pragma unroll 4
    for (int k = 0; k < Mn; ++k) {
        const float4 bx = sT[k][0];
        const float4 au = sT[k][1];   // {sinb, cosb, areaB, clsval}
        #pragma unroll
        for (int r = 0; r < R; ++r) {
            float iw = fminf(ax2[r], bx.z) - fmaxf(ax1[r], bx.x);
            float ih = fminf(ay2[r], bx.w) - fmaxf(ay1[r], bx.y);
            iw = fmaxf(iw, 0.f); ih = fmaxf(ih, 0.f);
            float inter = iw * ih;
            float ua = fmaxf(areaA[r] + au.z - inter, 1e-8f);
            float s = fabsf(sa[r] * au.y - ca[r] * au.x);   // |sin(aang-bang)|
            float av = inter * s;
            bool upd = (av * bestB[r] > bestA[r] * ua);
            bestA[r] = upd ? av : bestA[r];
            bestB[r] = upd ? ua : bestB[r];
            bestK[r] = upd ? k : bestK[r];
        }
    }

    float csum = 0.f, rsum = 0.f, pcnt = 0.f;

    #pragma unroll
    for (int r = 0; r < R; ++r) {
        if (!act[r]) continue;
        const int i = base + r * TPB;
        // iou >= 0.5  <=>  bestA >= 0.5*bestB   (bestB > 0; no division)
        const bool pos = bestA[r] >= 0.5f * bestB[r];
        const bool neg = bestA[r] <  0.4f * bestB[r];

        if (pos || neg) {
            const float4 au = sT[bestK[r]][1];
            const int ci = (int)au.w;
            float pv[9] = { c0[r].x, c0[r].y, c0[r].z, c0[r].w,
                            c1[r].x, c1[r].y, c1[r].z, c1[r].w, c8[r] };
            #pragma unroll
            for (int c = 0; c < Cn; ++c) {
                float p = fminf(fmaxf(pv[c], 1e-4f), 0.9999f);
                bool hit = pos && (c == ci);
                float t = hit ? (1.f - p) : p;   // focal base
                float m = hit ? p : (1.f - p);   // log argument
                float w = hit ? 0.25f : 0.75f;
                csum += w * t * t * (-__logf(m));
            }
        }

        if (pos) {
            pcnt += 1.f;
            const float4 gb = sT[bestK[r]][0];
            const float4 au = sT[bestK[r]][1];
            float aw = ax2[r] - ax1[r], ah = ay2[r] - ay1[r];
            float acx = ax1[r] + 0.5f * aw, acy = ay1[r] + 0.5f * ah;
            float gwr = gb.z - gb.x, ghr = gb.w - gb.y;
            float gcx = gb.x + 0.5f * gwr, gcy = gb.y + 0.5f * ghr;
            float gw = fmaxf(gwr, 1.f), gh = fmaxf(ghr, 1.f);
            float tt[5];
            tt[0] = ((gcx - acx) / aw) * 10.f;
            tt[1] = ((gcy - acy) / ah) * 10.f;
            tt[2] = logf(gw / aw) * 5.f;
            tt[3] = logf(gh / ah) * 5.f;
            tt[4] = tanf(au.w - aangv[r]);
            const float* rg = reg + ((size_t)b * An + i) * 5;
            #pragma unroll
            for (int j = 0; j < 5; ++j) {
                float d = fabsf(tt[j] - rg[j]);
                rsum += (d <= (1.f / 9.f)) ? (4.5f * d * d) : (d - (0.5f / 9.f));
            }
        }
    }

    // wave reduce (64 lanes) then cross-wave via LDS
    #pragma unroll
    for (int off = 32; off > 0; off >>= 1) {
        csum += __shfl_down(csum, off, 64);
        rsum += __shfl_down(rsum, off, 64);
        pcnt += __shfl_down(pcnt, off, 64);
    }
    const int wave = tid >> 6;
    if ((tid & 63) == 0) {
        sred[wave][0] = csum; sred[wave][1] = rsum; sred[wave][2] = pcnt;
    }
    __syncthreads();
    if (tid == 0) {
        float c = sred[0][0] + sred[1][0] + sred[2][0] + sred[3][0];
        float r = sred[0][1] + sred[1][1] + sred[2][1] + sred[3][1];
        float p = sred[0][2] + sred[1][2] + sred[2][2] + sred[3][2];
        const int j = b * GX + blockIdx.x;
        ws[j * 4 + 0] = c;   // unconditional writes: no memset needed
        ws[j * 4 + 1] = r;
        ws[j * 4 + 2] = p;
    }
}

// 8 waves, wave w reduces image w's GX partials; then thread 0 means over B.
__global__ __launch_bounds__(512) void focal_final(
    const float* __restrict__ ann,
    const float* __restrict__ ws,
    float* __restrict__ out)
{
    __shared__ float simg[Bn][2];
    const int tid = threadIdx.x;
    const int w = tid >> 6;      // image
    const int lane = tid & 63;

    float c = 0.f, r = 0.f, p = 0.f;
    for (int j = lane; j < GX; j += 64) {
        const int idx = (w * GX + j) * 4;
        c += ws[idx + 0]; r += ws[idx + 1]; p += ws[idx + 2];
    }
    // has_ann: lane k checks ann[w][k] (Mn==64 lanes exactly)
    float fl = ann[((size_t)w * Mn + lane) * 6 + 5];
    bool has = __any(fl != -1.0f);

    #pragma unroll
    for (int off = 32; off > 0; off >>= 1) {
        c += __shfl_down(c, off, 64);
        r += __shfl_down(r, off, 64);
        p += __shfl_down(p, off, 64);
    }
    if (lane == 0) {
        float cl = 0.f, rl = 0.f;
        if (has) {
            cl = c / fmaxf(p, 1.f);
            rl = (p > 0.f) ? r / fmaxf(p * 5.f, 1.f) : 0.f;
        }
        simg[w][0] = cl; simg[w][1] = rl;
    }
    __syncthreads();
    if (tid == 0) {
        float cl = 0.f, rl = 0.f;
        #pragma unroll
        for (int b = 0; b < Bn; ++b) { cl += simg[b][0]; rl += simg[b][1]; }
        out[0] = cl / (float)Bn;
        out[1] = rl / (float)Bn;
    }
}

extern "C" void kernel_launch(void* const* d_in, const int* in_sizes, int n_in,
                              void* d_out, int out_size, void* d_ws, size_t ws_size,
                              hipStream_t stream) {
    const float* cls     = (const float*)d_in[0];  // (B, A, C)
    const float* reg     = (const float*)d_in[1];  // (B, A, 5)
    const float* anchors = (const float*)d_in[2];  // (1, A, 5)
    const float* ann     = (const float*)d_in[3];  // (B, M, 6)
    float* out = (float*)d_out;
    float* ws  = (float*)d_ws;

    dim3 grid(GX, Bn);
    focal_main<<<grid, TPB, 0, stream>>>(cls, reg, anchors, ann, ws);
    focal_final<<<1, 512, 0, stream>>>(ann, ws, out);
}